// Round 3
// baseline (356.963 us; speedup 1.0000x reference)
//
#include <hip/hip_runtime.h>

#define C_DIM 256
#define NCODE 1024

typedef __bf16 bf16x8 __attribute__((ext_vector_type(8)));
typedef unsigned short u16x8 __attribute__((ext_vector_type(8)));
typedef float f32x4 __attribute__((ext_vector_type(4)));

// ws layout (byte offsets), all 256-aligned:
#define WS_ENORM 0         // f32[1024]                (4 KB)
#define WS_META  4096      // u32 count
#define WS_RLIST 8192      // u32[32768]               (128 KB)
#define WS_CODES 139264    // u32[32768]               (128 KB)
#define WS_EHI   270336    // bf16[1024*256] as u16    (512 KB)
#define WS_ELO   794624    // bf16[1024*256] as u16    (512 KB)

#define RESCUE_MARGIN 0.05f

__device__ __forceinline__ void bf16split(float x, unsigned short& h, unsigned short& l) {
    unsigned u  = __float_as_uint(x);
    unsigned rh = (u + 0x7FFFu + ((u >> 16) & 1u)) & 0xFFFF0000u;  // RNE to bf16
    float    hf = __uint_as_float(rh);
    float    lf = x - hf;                                          // exact
    unsigned ul = __float_as_uint(lf);
    h = (unsigned short)(rh >> 16);
    l = (unsigned short)((ul + 0x7FFFu + ((ul >> 16) & 1u)) >> 16);
}

// ---------- prep: split emb -> ehi/elo, enorm, reset rescue count ----------
__global__ __launch_bounds__(256) void prep_kernel(const float* __restrict__ emb,
                                                   unsigned short* __restrict__ ehi,
                                                   unsigned short* __restrict__ elo,
                                                   float* __restrict__ enorm,
                                                   unsigned* __restrict__ meta) {
    int gid = blockIdx.x * 256 + threadIdx.x;
    if (gid == 0) meta[0] = 0u;
    int row = gid >> 6, lane = gid & 63;           // 1024 rows, one wave each
    float4 v = reinterpret_cast<const float4*>(emb)[(size_t)row * 64 + lane];
    unsigned short h[4], l[4];
    bf16split(v.x, h[0], l[0]); bf16split(v.y, h[1], l[1]);
    bf16split(v.z, h[2], l[2]); bf16split(v.w, h[3], l[3]);
    uint2 hp, lp;
    hp.x = (unsigned)h[0] | ((unsigned)h[1] << 16);
    hp.y = (unsigned)h[2] | ((unsigned)h[3] << 16);
    lp.x = (unsigned)l[0] | ((unsigned)l[1] << 16);
    lp.y = (unsigned)l[2] | ((unsigned)l[3] << 16);
    *reinterpret_cast<uint2*>(ehi + (size_t)row * 256 + lane * 4) = hp;
    *reinterpret_cast<uint2*>(elo + (size_t)row * 256 + lane * 4) = lp;
    float s = v.x * v.x + v.y * v.y + v.z * v.z + v.w * v.w;
    #pragma unroll
    for (int off = 32; off; off >>= 1) s += __shfl_xor(s, off, 64);
    if (lane == 0) enorm[row] = s;
}

// ---------- main: 3-pass split-bf16 MFMA distances + top-2 argmin ----------
// 256 blocks x 512 thr (8 waves). Block = 128 rows; wave w = rows 16w..16w+15.
// A-frags (z hi/lo) in registers for full K=256; B-frags streamed from L2.
__global__ __launch_bounds__(512, 2) void vq_mfma_kernel(
    const float* __restrict__ z, const unsigned short* __restrict__ ehi,
    const unsigned short* __restrict__ elo, const float* __restrict__ enorm,
    unsigned* __restrict__ codes, unsigned* __restrict__ meta,
    unsigned* __restrict__ rlist) {
    __shared__ float enorm_s[NCODE];
    const int t    = threadIdx.x;
    const int w    = t >> 6;
    const int lane = t & 63;
    const int lr   = lane & 15;   // A row-in-frag / C col (code)
    const int lg   = lane >> 4;   // k-group / C row-group
    const long r0  = (long)blockIdx.x * 128;
    const long myrow = r0 + w * 16 + lr;

    for (int i = t; i < NCODE; i += 512) enorm_s[i] = enorm[i];

    // load + split A (my z row share): 8 k-steps x 8 elems
    bf16x8 ah[8], al[8];
    #pragma unroll
    for (int kc = 0; kc < 8; ++kc) {
        const float* zp = z + myrow * C_DIM + kc * 32 + lg * 8;
        u16x8 hv, lv;
        #pragma unroll
        for (int j = 0; j < 8; ++j) {
            unsigned short h, l;
            bf16split(zp[j], h, l);
            hv[j] = h; lv[j] = l;
        }
        ah[kc] = __builtin_bit_cast(bf16x8, hv);
        al[kc] = __builtin_bit_cast(bf16x8, lv);
    }
    __syncthreads();   // enorm_s ready

    float b1[4], b2[4]; unsigned i1[4];
    #pragma unroll
    for (int r = 0; r < 4; ++r) { b1[r] = 3.4e38f; b2[r] = 3.4e38f; i1[r] = 0; }

    for (int cb = 0; cb < 16; ++cb) {
        f32x4 acc[4];
        #pragma unroll
        for (int nf = 0; nf < 4; ++nf) acc[nf] = (f32x4){0.f, 0.f, 0.f, 0.f};

        #pragma unroll
        for (int kc = 0; kc < 8; ++kc) {
            bf16x8 bh[4], bl[4];
            #pragma unroll
            for (int nf = 0; nf < 4; ++nf) {
                const size_t eoff = ((size_t)(cb * 64 + nf * 16 + lr)) * C_DIM + kc * 32 + lg * 8;
                bh[nf] = *reinterpret_cast<const bf16x8*>(ehi + eoff);
                bl[nf] = *reinterpret_cast<const bf16x8*>(elo + eoff);
            }
            #pragma unroll
            for (int nf = 0; nf < 4; ++nf)
                acc[nf] = __builtin_amdgcn_mfma_f32_16x16x32_bf16(ah[kc], bh[nf], acc[nf], 0, 0, 0);
            #pragma unroll
            for (int nf = 0; nf < 4; ++nf)
                acc[nf] = __builtin_amdgcn_mfma_f32_16x16x32_bf16(ah[kc], bl[nf], acc[nf], 0, 0, 0);
            #pragma unroll
            for (int nf = 0; nf < 4; ++nf)
                acc[nf] = __builtin_amdgcn_mfma_f32_16x16x32_bf16(al[kc], bh[nf], acc[nf], 0, 0, 0);
        }

        // fold chunk into per-lane top-2 (codes ascend -> first-index ties)
        #pragma unroll
        for (int nf = 0; nf < 4; ++nf) {
            unsigned code = cb * 64 + nf * 16 + lr;
            float en = enorm_s[code];
            #pragma unroll
            for (int r = 0; r < 4; ++r) {
                float d = fmaf(-2.f, acc[nf][r], en);
                if (d < b1[r]) { b2[r] = b1[r]; b1[r] = d; i1[r] = code; }
                else if (d < b2[r]) { b2[r] = d; }
            }
        }
    }

    // cross-lane top-2 merge over the 16 lanes sharing a C row-group
    #pragma unroll
    for (int r = 0; r < 4; ++r) {
        #pragma unroll
        for (int off = 8; off; off >>= 1) {
            float    ob1 = __shfl_xor(b1[r], off, 64);
            float    ob2 = __shfl_xor(b2[r], off, 64);
            unsigned oi1 = (unsigned)__shfl_xor((int)i1[r], off, 64);
            if (ob1 < b1[r] || (ob1 == b1[r] && oi1 < i1[r])) {
                b2[r] = fminf(b1[r], ob2);
                b1[r] = ob1; i1[r] = oi1;
            } else {
                b2[r] = fminf(b2[r], ob1);
            }
        }
        if (lr == 0) {
            long row = r0 + w * 16 + lg * 4 + r;
            codes[row] = i1[r];
            if (b2[r] - b1[r] <= RESCUE_MARGIN) {
                unsigned slot = atomicAdd(meta, 1u);
                rlist[slot] = (unsigned)row;
            }
        }
    }
}

// ---------- rescue: exact fp32 re-argmin for flagged rows ----------
__global__ __launch_bounds__(256) void rescue_kernel(
    const float* __restrict__ z, const float* __restrict__ emb,
    const float* __restrict__ enorm, const unsigned* __restrict__ meta,
    const unsigned* __restrict__ rlist, unsigned* __restrict__ codes) {
    __shared__ float zrow[C_DIM];
    __shared__ float rd[256];
    __shared__ unsigned rix[256];
    const unsigned cnt = meta[0];
    for (unsigned li = blockIdx.x; li < cnt; li += gridDim.x) {
        unsigned row = rlist[li];
        __syncthreads();
        if (threadIdx.x < 64) {
            float4 v = reinterpret_cast<const float4*>(z)[(size_t)row * 64 + threadIdx.x];
            reinterpret_cast<float4*>(zrow)[threadIdx.x] = v;
        }
        __syncthreads();
        float bd = 3.4e38f; unsigned bi = 0;
        for (int c = threadIdx.x; c < NCODE; c += 256) {
            float acc = 0.f;
            const float4* ep = reinterpret_cast<const float4*>(emb + (size_t)c * C_DIM);
            const float4* zp = reinterpret_cast<const float4*>(zrow);
            #pragma unroll 8
            for (int k = 0; k < 64; ++k) {
                float4 e4 = ep[k], z4 = zp[k];
                acc = fmaf(z4.x, e4.x, acc); acc = fmaf(z4.y, e4.y, acc);
                acc = fmaf(z4.z, e4.z, acc); acc = fmaf(z4.w, e4.w, acc);
            }
            float d = fmaf(-2.f, acc, enorm[c]);
            if (d < bd) { bd = d; bi = (unsigned)c; }
        }
        rd[threadIdx.x] = bd; rix[threadIdx.x] = bi;
        __syncthreads();
        for (int s = 128; s; s >>= 1) {
            if (threadIdx.x < (unsigned)s) {
                float od = rd[threadIdx.x + s]; unsigned oi = rix[threadIdx.x + s];
                if (od < rd[threadIdx.x] ||
                    (od == rd[threadIdx.x] && oi < rix[threadIdx.x])) {
                    rd[threadIdx.x] = od; rix[threadIdx.x] = oi;
                }
            }
            __syncthreads();
        }
        if (threadIdx.x == 0) codes[row] = rix[0];
    }
}

// ---------- gather: z_q + indices ----------
__global__ __launch_bounds__(256) void gather_kernel(
    const float* __restrict__ emb, const unsigned* __restrict__ codes,
    float* __restrict__ zq, float* __restrict__ idx_out) {
    const long row = (long)blockIdx.x * 4 + (threadIdx.x >> 6);
    const int lane = threadIdx.x & 63;
    unsigned c = codes[row];
    float4 v = reinterpret_cast<const float4*>(emb)[(size_t)c * 64 + lane];
    reinterpret_cast<float4*>(zq)[row * 64 + lane] = v;
    if (lane == 0) idx_out[row] = (float)c;
}

extern "C" void kernel_launch(void* const* d_in, const int* in_sizes, int n_in,
                              void* d_out, int out_size, void* d_ws, size_t ws_size,
                              hipStream_t stream) {
    const float* z   = (const float*)d_in[0];
    const float* emb = (const float*)d_in[1];
    const int n = in_sizes[0] / C_DIM;   // 32768

    float* zq      = (float*)d_out;
    float* idx_out = zq + (size_t)n * C_DIM;

    char* ws = (char*)d_ws;
    float*          enorm = (float*)(ws + WS_ENORM);
    unsigned*       meta  = (unsigned*)(ws + WS_META);
    unsigned*       rlist = (unsigned*)(ws + WS_RLIST);
    unsigned*       codes = (unsigned*)(ws + WS_CODES);
    unsigned short* ehi   = (unsigned short*)(ws + WS_EHI);
    unsigned short* elo   = (unsigned short*)(ws + WS_ELO);

    prep_kernel<<<256, 256, 0, stream>>>(emb, ehi, elo, enorm, meta);
    vq_mfma_kernel<<<n / 128, 512, 0, stream>>>(z, ehi, elo, enorm, codes, meta, rlist);
    rescue_kernel<<<64, 256, 0, stream>>>(z, emb, enorm, meta, rlist, codes);
    gather_kernel<<<n / 4, 256, 0, stream>>>(emb, codes, zq, idx_out);
}